// Round 2
// baseline (573.066 us; speedup 1.0000x reference)
//
#include <hip/hip_runtime.h>

#define NROWS 800000
#define SEGROWS 100000
#define TPS 782          // tiles per segment: 781*128 + 32 = 100000
#define K1_BLOCKS 512    // 64 blocks/segment, all co-resident at 2 blocks/CU
#define K23_BLOCKS 625   // 5 chunks of 256 rows each, all co-resident at 3/CU
// ws float layout:
//   [0..4096)     M2 (atomic-accumulated by k1)
//   [4096..4608)  segment sums (atomic-accumulated by k1)

typedef __attribute__((ext_vector_type(8))) short bf16x8;
typedef __attribute__((ext_vector_type(4))) float f32x4;
typedef __attribute__((ext_vector_type(4))) short short4v;

__device__ inline unsigned short f2bf(float f) { // RNE fp32 -> bf16
    unsigned u = __builtin_bit_cast(unsigned, f);
    return (unsigned short)((u + 0x7FFFu + ((u >> 16) & 1u)) >> 16);
}

// ---------------- K0: zero the atomic accumulators ----------------
__global__ void kzero(float* __restrict__ p) {
    int t = blockIdx.x * 256 + threadIdx.x;
    if (t < 4608) p[t] = 0.f;
}

// ---------------- K1: M2 = X^T X (bf16 MFMA) + segment sums ----------------
// A-frag == B-frag trick: frag(l,j) = x[r0+8*(l>>4)+j][c0+(l&15)] serves both operands.
// 512 blocks: block (seg = blk>>6) handles tiles jj, jj+64, ... of its segment.
__global__ __launch_bounds__(256, 2)
void k1_stats(const float* __restrict__ x, float* __restrict__ m2g, float* __restrict__ ssumg)
{
    __shared__ __align__(16) float smem[5120];   // 20 KB: xt (17408 B) then reduce bufs
    short* xt = (short*)smem;                    // xt[col][row], stride 136 shorts (128+8 pad)
    const float4* X4 = (const float4*)x;
    int t = threadIdx.x, w = t >> 6, lane = t & 63;
    int c4 = t & 15, g = t >> 4;
    const int seg = blockIdx.x >> 6, jj = blockIdx.x & 63;

    f32x4 acc[4][4];
#pragma unroll
    for (int p = 0; p < 4; ++p)
#pragma unroll
        for (int q = 0; q < 4; ++q) acc[p][q] = (f32x4){0.f, 0.f, 0.f, 0.f};
    float s0 = 0, s1 = 0, s2 = 0, s3 = 0;

    for (int tl = jj; tl < TPS; tl += 64) {      // all tiles segment-pure
        const size_t r0 = (size_t)seg * SEGROWS + (size_t)tl * 128;
        const int nr = (tl == TPS - 1) ? 32 : 128;
        __syncthreads();                         // previous tile's frag reads done
#pragma unroll
        for (int h = 0; h < 2; ++h) {            // piece: 4 rows x 4 cols, transposed store
            int rg = 8 * g + 4 * h;
            float4 v[4];
#pragma unroll
            for (int i = 0; i < 4; ++i) {
                int r = rg + i;
                if (r < nr) {
                    v[i] = X4[(r0 + r) * 16 + c4];
                    s0 += v[i].x; s1 += v[i].y; s2 += v[i].z; s3 += v[i].w;
                } else v[i] = make_float4(0.f, 0.f, 0.f, 0.f);
            }
#pragma unroll
            for (int j = 0; j < 4; ++j) {        // col 4*c4+j gets rows rg..rg+3
                short4v pk;
                pk[0] = (short)f2bf(((const float*)&v[0])[j]);
                pk[1] = (short)f2bf(((const float*)&v[1])[j]);
                pk[2] = (short)f2bf(((const float*)&v[2])[j]);
                pk[3] = (short)f2bf(((const float*)&v[3])[j]);
                *(short4v*)&xt[(4 * c4 + j) * 136 + rg] = pk;
            }
        }
        __syncthreads();
        // wave w owns k-chunk rows 32w..32w+31; one frag per 16-col tile
        bf16x8 f[4];
#pragma unroll
        for (int c0 = 0; c0 < 4; ++c0)
            f[c0] = *(const bf16x8*)&xt[(16 * c0 + (lane & 15)) * 136 + 32 * w + 8 * (lane >> 4)];
#pragma unroll
        for (int p = 0; p < 4; ++p)
#pragma unroll
            for (int q = 0; q < 4; ++q)
                acc[p][q] = __builtin_amdgcn_mfma_f32_16x16x32_bf16(f[p], f[q], acc[p][q], 0, 0, 0);
    }

    __syncthreads();                             // xt dead; reuse smem
    ((float4*)(smem + 4096))[t] = make_float4(s0, s1, s2, s3);
    int qd = lane >> 4, cl = lane & 15;
    if (w == 0) {
#pragma unroll
        for (int p = 0; p < 4; ++p)
#pragma unroll
            for (int q = 0; q < 4; ++q)
#pragma unroll
                for (int i = 0; i < 4; ++i)
                    smem[(16 * p + 4 * qd + i) * 64 + 16 * q + cl] = acc[p][q][i];
    }
    __syncthreads();
    if (t < 64) {                                // wave0: segment-sum reduce + atomic
        int cc4 = t >> 2, ii = t & 3;
        float s = 0;
#pragma unroll
        for (int u = 0; u < 16; ++u) s += smem[4096 + 4 * (cc4 + 16 * u) + ii];
        atomicAdd(&ssumg[seg * 64 + t], s);
    }
    for (int ww = 1; ww < 4; ++ww) {
        if (w == ww) {
#pragma unroll
            for (int p = 0; p < 4; ++p)
#pragma unroll
                for (int q = 0; q < 4; ++q)
#pragma unroll
                    for (int i = 0; i < 4; ++i)
                        smem[(16 * p + 4 * qd + i) * 64 + 16 * q + cl] += acc[p][q][i];
        }
        __syncthreads();
    }
    // rotate atomic start address per block to decorrelate same-address bursts
#pragma unroll
    for (int ii = 0; ii < 16; ++ii) {
        int f2 = t + 256 * ((ii + blockIdx.x) & 15);
        atomicAdd(&m2g[f2], smem[f2]);
    }
}

// ---------------- K23: per-block tiny algebra (redundant) + GEMM ----------------
// Phase B == old k2b, computed redundantly by every block straight into LDS.
// Phase C == old k3, 5 contiguous 256-row chunks per block.
__global__ __launch_bounds__(256, 3)
void k23(const float* __restrict__ x, const int* __restrict__ o,
         const float* __restrict__ w2, const float* __restrict__ b2,
         const float* __restrict__ w1, const float* __restrict__ b1,
         const float* __restrict__ gamma, const float* __restrict__ beta,
         const float* __restrict__ m2, const float* __restrict__ ssum,
         float* __restrict__ out)
{
    __shared__ float means[512], hb[512], cv[512], q1p[256];
    __shared__ float Sx[64], muS[64], sS[64], cnts[8];
    __shared__ __align__(16) short bt[64 * 72];  // W' bf16, stride 72 shorts
    __shared__ float tbs[512];                   // per-seg bias

    const int t = threadIdx.x, lane = t & 63, w = t >> 6;

    // ---------------- phase B ----------------
    {
        if (t < 8) cnts[t] = (float)(o[t] - (t ? o[t - 1] : 0));
        __syncthreads();
        for (int i = t; i < 512; i += 256) means[i] = ssum[i] / cnts[i >> 6];
        __syncthreads();
        const int c = t & 63, g = t >> 6;
        for (int b = g; b < 8; b += 4) {
            float a = b2[c];
            for (int k = 0; k < 64; ++k) a = fmaf(means[b * 64 + k], w2[c * 64 + k], a);
            hb[b * 64 + c] = fmaxf(a, 0.f);
        }
        __syncthreads();
        for (int b = g; b < 8; b += 4) {
            float a = b1[c];
            for (int k = 0; k < 64; ++k) a = fmaf(hb[b * 64 + k], w1[c * 128 + 64 + k], a);
            cv[b * 64 + c] = a;
        }
        __syncthreads();
        if (t < 64) {
            float s = 0;
            for (int b = 0; b < 8; ++b) s += ssum[b * 64 + t];
            Sx[t] = s;
        }
        __syncthreads();
        {
            float p = 0;
            for (int j = g * 16; j < g * 16 + 16; ++j) {
                float vj = 0;
                for (int k = 0; k < 64; ++k) vj = fmaf(w1[c * 128 + k], m2[j * 64 + k], vj);
                p = fmaf(w1[c * 128 + j], vj, p);
            }
            q1p[g * 64 + c] = p;
        }
        __syncthreads();
        if (t < 64) {
            const float Nf = (float)NROWS;
            float mu = 0;
            for (int k = 0; k < 64; ++k) mu = fmaf(w1[t * 128 + k], Sx[k], mu);
            float q2 = 0, q3 = 0, msum = 0;
            for (int b = 0; b < 8; ++b) {
                float gv = cv[b * 64 + t];
                msum += cnts[b] * gv;
                q3 = fmaf(cnts[b] * gv, gv, q3);
                float dot = 0;
                for (int k = 0; k < 64; ++k) dot = fmaf(w1[t * 128 + k], ssum[b * 64 + k], dot);
                q2 = fmaf(2.f * gv, dot, q2);
            }
            mu = (mu + msum) / Nf;
            float q1 = q1p[t] + q1p[64 + t] + q1p[128 + t] + q1p[192 + t];
            float var = (q1 + q2 + q3) / Nf - mu * mu;
            float s = gamma[t] * rsqrtf(var + 1e-5f);
            muS[t] = mu; sS[t] = s;
        }
        __syncthreads();
        for (int f = t; f < 4096; f += 256)      // W'[c][k] bf16 straight into LDS
            bt[(f >> 6) * 72 + (f & 63)] = (short)f2bf(w1[(f >> 6) * 128 + (f & 63)] * sS[f >> 6]);
        for (int f = t; f < 512; f += 256)
            tbs[f] = (cv[f] - muS[f & 63]) * sS[f & 63] + beta[f & 63];
        __syncthreads();
    }

    // ---------------- phase C: out = relu(x @ W'^T + tb[seg]) via bf16 MFMA ----------------
    {
        const int cl = lane & 15, qd = lane >> 4;
        bf16x8 B[4][2];
#pragma unroll
        for (int n = 0; n < 4; ++n)
#pragma unroll
            for (int k0 = 0; k0 < 2; ++k0)
                B[n][k0] = *(const bf16x8*)&bt[(16 * n + cl) * 72 + 32 * k0 + 8 * qd];

        for (int chunk = blockIdx.x * 5; chunk < blockIdx.x * 5 + 5; ++chunk) {
            const int rbase = chunk * 256 + 64 * w;
            f32x4 acc[4][4];
#pragma unroll
            for (int m = 0; m < 4; ++m)
#pragma unroll
                for (int n = 0; n < 4; ++n) acc[m][n] = (f32x4){0.f, 0.f, 0.f, 0.f};

#pragma unroll
            for (int m = 0; m < 4; ++m) {
                // A-frags straight from global: lane reads 32 B contiguous fp32 per frag
                const float* rp = x + (size_t)(rbase + 16 * m + cl) * 64 + 8 * qd;
                float4 u0 = *(const float4*)(rp);
                float4 u1 = *(const float4*)(rp + 4);
                float4 u2 = *(const float4*)(rp + 32);
                float4 u3 = *(const float4*)(rp + 36);
                bf16x8 A0, A1;
                A0[0] = (short)f2bf(u0.x); A0[1] = (short)f2bf(u0.y);
                A0[2] = (short)f2bf(u0.z); A0[3] = (short)f2bf(u0.w);
                A0[4] = (short)f2bf(u1.x); A0[5] = (short)f2bf(u1.y);
                A0[6] = (short)f2bf(u1.z); A0[7] = (short)f2bf(u1.w);
                A1[0] = (short)f2bf(u2.x); A1[1] = (short)f2bf(u2.y);
                A1[2] = (short)f2bf(u2.z); A1[3] = (short)f2bf(u2.w);
                A1[4] = (short)f2bf(u3.x); A1[5] = (short)f2bf(u3.y);
                A1[6] = (short)f2bf(u3.z); A1[7] = (short)f2bf(u3.w);
#pragma unroll
                for (int n = 0; n < 4; ++n) {
                    acc[m][n] = __builtin_amdgcn_mfma_f32_16x16x32_bf16(A0, B[n][0], acc[m][n], 0, 0, 0);
                    acc[m][n] = __builtin_amdgcn_mfma_f32_16x16x32_bf16(A1, B[n][1], acc[m][n], 0, 0, 0);
                }
            }

            // epilogue: +tb[seg], relu, direct stores (16 lanes = 64 B runs)
            const int seg0 = rbase / SEGROWS;
            const int bnd = (seg0 + 1) * SEGROWS;
            const int seg1 = min(seg0 + 1, 7);
            float tA[4], tB[4];
#pragma unroll
            for (int n = 0; n < 4; ++n) {
                tA[n] = tbs[seg0 * 64 + 16 * n + cl];
                tB[n] = tbs[seg1 * 64 + 16 * n + cl];
            }
#pragma unroll
            for (int m = 0; m < 4; ++m)
#pragma unroll
                for (int i = 0; i < 4; ++i) {
                    int grow = rbase + 16 * m + 4 * qd + i;
                    bool hi = grow >= bnd;
#pragma unroll
                    for (int n = 0; n < 4; ++n) {
                        float tv = hi ? tB[n] : tA[n];
                        float vv = fmaxf(acc[m][n][i] + tv, 0.f);
                        out[(size_t)grow * 64 + 16 * n + cl] = vv;
                    }
                }
        }
    }
}

extern "C" void kernel_launch(void* const* d_in, const int* in_sizes, int n_in,
                              void* d_out, int out_size, void* d_ws, size_t ws_size,
                              hipStream_t stream)
{
    const float* x  = (const float*)d_in[0];
    const int*   o  = (const int*)d_in[1];
    const float* w2 = (const float*)d_in[2];
    const float* b2 = (const float*)d_in[3];
    const float* w1 = (const float*)d_in[4];
    const float* b1 = (const float*)d_in[5];
    const float* gm = (const float*)d_in[6];
    const float* bt = (const float*)d_in[7];
    float* out = (float*)d_out;
    float* ws  = (float*)d_ws;

    float* m2g  = ws;
    float* ssum = ws + 4096;

    kzero<<<18, 256, 0, stream>>>(ws);
    k1_stats<<<K1_BLOCKS, 256, 0, stream>>>(x, m2g, ssum);
    k23<<<K23_BLOCKS, 256, 0, stream>>>(x, o, w2, b2, w1, b1, gm, bt, m2g, ssum, out);
}

// Round 3
// 443.785 us; speedup vs baseline: 1.2913x; 1.2913x over previous
//
#include <hip/hip_runtime.h>

#define NROWS 800000
#define SEGROWS 100000
#define K1_BLOCKS 800
#define K1_ROWS 1000
// ws float layout:
//   [0..4096)     M2 (atomic-accumulated by k1)
//   [4096..4608)  segment sums (atomic-accumulated by k1)
//   [4608..5120)  tb fp32 (written by k2b)
//   [5120..7168)  wpb: W' as bf16 ushort[64*64], row-major [c][k] (written by k2b)

typedef __attribute__((ext_vector_type(8))) short bf16x8;
typedef __attribute__((ext_vector_type(4))) float f32x4;
typedef __attribute__((ext_vector_type(4))) short short4v;

__device__ inline unsigned short f2bf(float f) { // RNE fp32 -> bf16
    unsigned u = __builtin_bit_cast(unsigned, f);
    return (unsigned short)((u + 0x7FFFu + ((u >> 16) & 1u)) >> 16);
}

// ---------------- K0: zero the atomic accumulators ----------------
__global__ void kzero(float* __restrict__ p) {
    int t = blockIdx.x * 256 + threadIdx.x;
    if (t < 4608) p[t] = 0.f;
}

// ---------------- K1: M2 = X^T X (bf16 MFMA) + segment sums ----------------
// A-frag == B-frag trick: frag(l,j) = x[r0+8*(l>>4)+j][c0+(l&15)] serves both operands.
__global__ __launch_bounds__(256, 2)
void k1_stats(const float* __restrict__ x, float* __restrict__ m2g, float* __restrict__ ssumg)
{
    __shared__ __align__(16) float smem[5120];   // 20 KB: xt (17408 B) then reduce bufs
    short* xt = (short*)smem;                    // xt[col][row], stride 136 shorts (128+8 pad)
    const float4* X4 = (const float4*)x;
    int t = threadIdx.x, w = t >> 6, lane = t & 63;
    int c4 = t & 15, g = t >> 4;
    size_t r0 = (size_t)blockIdx.x * K1_ROWS;
    int seg = (int)(r0 / SEGROWS);               // blocks are segment-aligned (1000 | 100000)

    f32x4 acc[4][4];
#pragma unroll
    for (int p = 0; p < 4; ++p)
#pragma unroll
        for (int q = 0; q < 4; ++q) acc[p][q] = (f32x4){0.f, 0.f, 0.f, 0.f};
    float s0 = 0, s1 = 0, s2 = 0, s3 = 0;

    for (int tile = 0; tile < K1_ROWS; tile += 128) {
        int nr = min(128, K1_ROWS - tile);       // 128 or 104 (104 % 8 == 0: clean pieces)
        __syncthreads();                         // previous tile's frag reads done
#pragma unroll
        for (int h = 0; h < 2; ++h) {            // piece: 4 rows x 4 cols, transposed store
            int rg = 8 * g + 4 * h;
            float4 v[4];
#pragma unroll
            for (int i = 0; i < 4; ++i) {
                int r = rg + i;
                if (r < nr) {
                    v[i] = X4[(r0 + tile + r) * 16 + c4];
                    s0 += v[i].x; s1 += v[i].y; s2 += v[i].z; s3 += v[i].w;
                } else v[i] = make_float4(0.f, 0.f, 0.f, 0.f);
            }
#pragma unroll
            for (int j = 0; j < 4; ++j) {        // col 4*c4+j gets rows rg..rg+3
                short4v pk;
                pk[0] = (short)f2bf(((const float*)&v[0])[j]);
                pk[1] = (short)f2bf(((const float*)&v[1])[j]);
                pk[2] = (short)f2bf(((const float*)&v[2])[j]);
                pk[3] = (short)f2bf(((const float*)&v[3])[j]);
                *(short4v*)&xt[(4 * c4 + j) * 136 + rg] = pk;
            }
        }
        __syncthreads();
        // wave w owns k-chunk rows 32w..32w+31; one frag per 16-col tile
        bf16x8 f[4];
#pragma unroll
        for (int c0 = 0; c0 < 4; ++c0)
            f[c0] = *(const bf16x8*)&xt[(16 * c0 + (lane & 15)) * 136 + 32 * w + 8 * (lane >> 4)];
#pragma unroll
        for (int p = 0; p < 4; ++p)
#pragma unroll
            for (int q = 0; q < 4; ++q)
                acc[p][q] = __builtin_amdgcn_mfma_f32_16x16x32_bf16(f[p], f[q], acc[p][q], 0, 0, 0);
    }

    __syncthreads();                             // xt dead; reuse smem
    ((float4*)(smem + 4096))[t] = make_float4(s0, s1, s2, s3);
    int qd = lane >> 4, cl = lane & 15;
    if (w == 0) {
#pragma unroll
        for (int p = 0; p < 4; ++p)
#pragma unroll
            for (int q = 0; q < 4; ++q)
#pragma unroll
                for (int i = 0; i < 4; ++i)
                    smem[(16 * p + 4 * qd + i) * 64 + 16 * q + cl] = acc[p][q][i];
    }
    __syncthreads();
    if (t < 64) {                                // wave0: segment-sum reduce + atomic
        int cc4 = t >> 2, ii = t & 3;
        float s = 0;
#pragma unroll
        for (int u = 0; u < 16; ++u) s += smem[4096 + 4 * (cc4 + 16 * u) + ii];
        atomicAdd(&ssumg[seg * 64 + t], s);
    }
    for (int ww = 1; ww < 4; ++ww) {
        if (w == ww) {
#pragma unroll
            for (int p = 0; p < 4; ++p)
#pragma unroll
                for (int q = 0; q < 4; ++q)
#pragma unroll
                    for (int i = 0; i < 4; ++i)
                        smem[(16 * p + 4 * qd + i) * 64 + 16 * q + cl] += acc[p][q][i];
        }
        __syncthreads();
    }
    for (int f2 = t; f2 < 4096; f2 += 256) atomicAdd(&m2g[f2], smem[f2]);
}

// ---------------- K2b: tiny algebra -> wpb (bf16), tb ----------------
// Single block, but ALL matrix operands staged to LDS in one parallel burst
// (w1 32KB + w2 16KB + m2 16KB + ssum 2KB) so the fmaf loops never touch
// global: collapses ~2500 serialized global-latency hits to one round-trip.
__global__ __launch_bounds__(256)
void k2b_solve(const int* __restrict__ o,
               const float* __restrict__ w2, const float* __restrict__ b2,
               const float* __restrict__ w1, const float* __restrict__ b1,
               const float* __restrict__ gamma, const float* __restrict__ beta,
               const float* __restrict__ m2, const float* __restrict__ ssum,
               unsigned short* __restrict__ wpb, float* __restrict__ tbout)
{
    __shared__ __align__(16) float w1s[8192];    // 32 KB  w1[c][128]
    __shared__ __align__(16) float w2s[4096];    // 16 KB  w2[c][64]
    __shared__ __align__(16) float m2s[4096];    // 16 KB  M2[j][64]
    __shared__ __align__(16) float ssums[512];
    __shared__ float means[512], hb[512], cv[512], q1p[256];
    __shared__ float Sx[64], muS[64], sS[64], cnts[8];

    int t = threadIdx.x;
    // ---- parallel LDS staging burst (all loads independent, one round trip) ----
    for (int i = t; i < 2048; i += 256) ((float4*)w1s)[i] = ((const float4*)w1)[i];
    for (int i = t; i < 1024; i += 256) ((float4*)w2s)[i] = ((const float4*)w2)[i];
    for (int i = t; i < 1024; i += 256) ((float4*)m2s)[i] = ((const float4*)m2)[i];
    for (int i = t; i < 128;  i += 256) ((float4*)ssums)[i] = ((const float4*)ssum)[i];
    if (t < 8) cnts[t] = (float)(o[t] - (t ? o[t - 1] : 0));
    __syncthreads();

    for (int i = t; i < 512; i += 256) means[i] = ssums[i] / cnts[i >> 6];
    __syncthreads();
    int c = t & 63, g = t >> 6;
    for (int b = g; b < 8; b += 4) {
        float a = b2[c];
        for (int k = 0; k < 64; ++k) a = fmaf(means[b * 64 + k], w2s[c * 64 + k], a);
        hb[b * 64 + c] = fmaxf(a, 0.f);
    }
    __syncthreads();
    for (int b = g; b < 8; b += 4) {
        float a = b1[c];
        for (int k = 0; k < 64; ++k) a = fmaf(hb[b * 64 + k], w1s[c * 128 + 64 + k], a);
        cv[b * 64 + c] = a;
    }
    __syncthreads();
    if (t < 64) {
        float s = 0;
        for (int b = 0; b < 8; ++b) s += ssums[b * 64 + t];
        Sx[t] = s;
    }
    __syncthreads();
    {
        float p = 0;
        for (int j = g * 16; j < g * 16 + 16; ++j) {
            float vj = 0;
            for (int k = 0; k < 64; ++k) vj = fmaf(w1s[c * 128 + k], m2s[j * 64 + k], vj);
            p = fmaf(w1s[c * 128 + j], vj, p);
        }
        q1p[g * 64 + c] = p;
    }
    __syncthreads();
    if (t < 64) {
        const float Nf = (float)NROWS;
        float mu = 0;
        for (int k = 0; k < 64; ++k) mu = fmaf(w1s[t * 128 + k], Sx[k], mu);
        float q2 = 0, q3 = 0, msum = 0;
        for (int b = 0; b < 8; ++b) {
            float gv = cv[b * 64 + t];
            msum += cnts[b] * gv;
            q3 = fmaf(cnts[b] * gv, gv, q3);
            float dot = 0;
            for (int k = 0; k < 64; ++k) dot = fmaf(w1s[t * 128 + k], ssums[b * 64 + k], dot);
            q2 = fmaf(2.f * gv, dot, q2);
        }
        mu = (mu + msum) / Nf;
        float q1 = q1p[t] + q1p[64 + t] + q1p[128 + t] + q1p[192 + t];
        float var = (q1 + q2 + q3) / Nf - mu * mu;
        float s = gamma[t] * rsqrtf(var + 1e-5f);
        muS[t] = mu; sS[t] = s;
    }
    __syncthreads();
    for (int f = t; f < 4096; f += 256)         // W'[c][k] bf16, row-major (B-frag ready)
        wpb[f] = f2bf(w1s[(f >> 6) * 128 + (f & 63)] * sS[f >> 6]);
    for (int f = t; f < 512; f += 256)
        tbout[f] = (cv[f] - muS[f & 63]) * sS[f & 63] + beta[f & 63];
}

// ---------------- K3: out = relu(x @ W'^T + tb[seg]) via bf16 MFMA ----------------
__global__ __launch_bounds__(256, 3)
void k3_gemm(const float* __restrict__ x, const unsigned short* __restrict__ wpb,
             const float* __restrict__ tb, float* __restrict__ out)
{
    __shared__ __align__(16) short bt[64 * 72];  // W' tile, stride 72 shorts
    __shared__ float tbs[512];
    int t = threadIdx.x, lane = t & 63, w = t >> 6;
    size_t r0 = (size_t)blockIdx.x * 256;

    for (int f = t; f < 512; f += 256) {         // stage W' (8 KB) to LDS
        int c = f >> 3, kg = f & 7;
        uint4 vv = ((const uint4*)wpb)[f];
        *(uint4*)&bt[c * 72 + kg * 8] = vv;
    }
    for (int f = t; f < 512; f += 256) tbs[f] = tb[f];
    __syncthreads();

    int cl = lane & 15, qd = lane >> 4;
    bf16x8 B[4][2];
#pragma unroll
    for (int n = 0; n < 4; ++n)
#pragma unroll
        for (int k0 = 0; k0 < 2; ++k0)
            B[n][k0] = *(const bf16x8*)&bt[(16 * n + cl) * 72 + 32 * k0 + 8 * qd];

    int rbase = (int)r0 + 64 * w;
    f32x4 acc[4][4];
#pragma unroll
    for (int m = 0; m < 4; ++m)
#pragma unroll
        for (int n = 0; n < 4; ++n) acc[m][n] = (f32x4){0.f, 0.f, 0.f, 0.f};

#pragma unroll
    for (int m = 0; m < 4; ++m) {
        // A-frags straight from global: lane reads 32 B contiguous fp32 per frag
        const float* rp = x + (size_t)(rbase + 16 * m + cl) * 64 + 8 * qd;
        float4 u0 = *(const float4*)(rp);
        float4 u1 = *(const float4*)(rp + 4);
        float4 u2 = *(const float4*)(rp + 32);
        float4 u3 = *(const float4*)(rp + 36);
        bf16x8 A0, A1;
        A0[0] = (short)f2bf(u0.x); A0[1] = (short)f2bf(u0.y);
        A0[2] = (short)f2bf(u0.z); A0[3] = (short)f2bf(u0.w);
        A0[4] = (short)f2bf(u1.x); A0[5] = (short)f2bf(u1.y);
        A0[6] = (short)f2bf(u1.z); A0[7] = (short)f2bf(u1.w);
        A1[0] = (short)f2bf(u2.x); A1[1] = (short)f2bf(u2.y);
        A1[2] = (short)f2bf(u2.z); A1[3] = (short)f2bf(u2.w);
        A1[4] = (short)f2bf(u3.x); A1[5] = (short)f2bf(u3.y);
        A1[6] = (short)f2bf(u3.z); A1[7] = (short)f2bf(u3.w);
#pragma unroll
        for (int n = 0; n < 4; ++n) {
            acc[m][n] = __builtin_amdgcn_mfma_f32_16x16x32_bf16(A0, B[n][0], acc[m][n], 0, 0, 0);
            acc[m][n] = __builtin_amdgcn_mfma_f32_16x16x32_bf16(A1, B[n][1], acc[m][n], 0, 0, 0);
        }
    }

    // epilogue: +tb[seg], relu, direct stores (16 lanes = 64 B runs)
    int seg0 = rbase / SEGROWS;
    int bnd = (seg0 + 1) * SEGROWS;
    int seg1 = min(seg0 + 1, 7);
    float tA[4], tB[4];
#pragma unroll
    for (int n = 0; n < 4; ++n) {
        tA[n] = tbs[seg0 * 64 + 16 * n + cl];
        tB[n] = tbs[seg1 * 64 + 16 * n + cl];
    }
#pragma unroll
    for (int m = 0; m < 4; ++m)
#pragma unroll
        for (int i = 0; i < 4; ++i) {
            int grow = rbase + 16 * m + 4 * qd + i;
            bool hi = grow >= bnd;
#pragma unroll
            for (int n = 0; n < 4; ++n) {
                float tv = hi ? tB[n] : tA[n];
                float vv = fmaxf(acc[m][n][i] + tv, 0.f);
                out[(size_t)grow * 64 + 16 * n + cl] = vv;
            }
        }
}

extern "C" void kernel_launch(void* const* d_in, const int* in_sizes, int n_in,
                              void* d_out, int out_size, void* d_ws, size_t ws_size,
                              hipStream_t stream)
{
    const float* x  = (const float*)d_in[0];
    const int*   o  = (const int*)d_in[1];
    const float* w2 = (const float*)d_in[2];
    const float* b2 = (const float*)d_in[3];
    const float* w1 = (const float*)d_in[4];
    const float* b1 = (const float*)d_in[5];
    const float* gm = (const float*)d_in[6];
    const float* bt = (const float*)d_in[7];
    float* out = (float*)d_out;
    float* ws  = (float*)d_ws;

    float*          m2g  = ws;
    float*          ssum = ws + 4096;
    float*          tbv  = ws + 4608;
    unsigned short* wpb  = (unsigned short*)(ws + 5120);

    kzero<<<18, 256, 0, stream>>>(ws);
    k1_stats<<<K1_BLOCKS, 256, 0, stream>>>(x, m2g, ssum);
    k2b_solve<<<1, 256, 0, stream>>>(o, w2, b2, w1, b1, gm, bt, m2g, ssum, wpb, tbv);
    k3_gemm<<<3125, 256, 0, stream>>>(x, wpb, tbv, out);
}

// Round 4
// 434.069 us; speedup vs baseline: 1.3202x; 1.0224x over previous
//
#include <hip/hip_runtime.h>

#define NROWS 800000
#define SEGROWS 100000
#define K1_BLOCKS 800
#define K1_ROWS 1000
// ws float layout:
//   [0..32768)       M2 per-segment partials: 8 x 4096 (atomic, fan-in 100)
//   [32768..33280)   segment sums (atomic, fan-in 100)
//   [33280..33792)   tb fp32 (written by k2b)
//   [33792..35840)   wpb: W' as bf16 ushort[64*64], row-major [c][k] (k2b)

typedef __attribute__((ext_vector_type(8))) short bf16x8;
typedef __attribute__((ext_vector_type(4))) float f32x4;
typedef __attribute__((ext_vector_type(4))) short short4v;

__device__ inline unsigned short f2bf(float f) { // RNE fp32 -> bf16
    unsigned u = __builtin_bit_cast(unsigned, f);
    return (unsigned short)((u + 0x7FFFu + ((u >> 16) & 1u)) >> 16);
}

// ---------------- K0: zero the atomic accumulators ----------------
__global__ void kzero(float* __restrict__ p) {
    int t = blockIdx.x * 256 + threadIdx.x;
    if (t < 33280) p[t] = 0.f;
}

// ---------------- K1: M2 = X^T X (bf16 MFMA) + segment sums ----------------
// A-frag == B-frag trick: frag(l,j) = x[r0+8*(l>>4)+j][c0+(l&15)] serves both operands.
// M2 accumulated into per-SEGMENT partial buffers (fan-in 100 instead of 800).
__global__ __launch_bounds__(256, 2)
void k1_stats(const float* __restrict__ x, float* __restrict__ m2p, float* __restrict__ ssumg)
{
    __shared__ __align__(16) float smem[5120];   // 20 KB: xt (17408 B) then reduce bufs
    short* xt = (short*)smem;                    // xt[col][row], stride 136 shorts (128+8 pad)
    const float4* X4 = (const float4*)x;
    int t = threadIdx.x, w = t >> 6, lane = t & 63;
    int c4 = t & 15, g = t >> 4;
    size_t r0 = (size_t)blockIdx.x * K1_ROWS;
    int seg = (int)(r0 / SEGROWS);               // blocks are segment-aligned (1000 | 100000)

    f32x4 acc[4][4];
#pragma unroll
    for (int p = 0; p < 4; ++p)
#pragma unroll
        for (int q = 0; q < 4; ++q) acc[p][q] = (f32x4){0.f, 0.f, 0.f, 0.f};
    float s0 = 0, s1 = 0, s2 = 0, s3 = 0;

    for (int tile = 0; tile < K1_ROWS; tile += 128) {
        int nr = min(128, K1_ROWS - tile);       // 128 or 104 (104 % 8 == 0: clean pieces)
        __syncthreads();                         // previous tile's frag reads done
        if (nr == 128) {
            // fast path: all 8 row-loads unconditional, issued back-to-back
            float4 v[8];
#pragma unroll
            for (int i = 0; i < 8; ++i)
                v[i] = X4[(r0 + tile + 8 * g + i) * 16 + c4];
#pragma unroll
            for (int i = 0; i < 8; ++i) {
                s0 += v[i].x; s1 += v[i].y; s2 += v[i].z; s3 += v[i].w;
            }
#pragma unroll
            for (int j = 0; j < 4; ++j) {        // col 4*c4+j gets rows 8g..8g+7
                bf16x8 pk;
#pragma unroll
                for (int i = 0; i < 8; ++i)
                    pk[i] = (short)f2bf(((const float*)&v[i])[j]);
                *(bf16x8*)&xt[(4 * c4 + j) * 136 + 8 * g] = pk;
            }
        } else {
            // tail tile (104 rows): guarded path
#pragma unroll
            for (int h = 0; h < 2; ++h) {
                int rg = 8 * g + 4 * h;
                float4 v[4];
#pragma unroll
                for (int i = 0; i < 4; ++i) {
                    int r = rg + i;
                    if (r < nr) {
                        v[i] = X4[(r0 + tile + r) * 16 + c4];
                        s0 += v[i].x; s1 += v[i].y; s2 += v[i].z; s3 += v[i].w;
                    } else v[i] = make_float4(0.f, 0.f, 0.f, 0.f);
                }
#pragma unroll
                for (int j = 0; j < 4; ++j) {
                    short4v pk;
                    pk[0] = (short)f2bf(((const float*)&v[0])[j]);
                    pk[1] = (short)f2bf(((const float*)&v[1])[j]);
                    pk[2] = (short)f2bf(((const float*)&v[2])[j]);
                    pk[3] = (short)f2bf(((const float*)&v[3])[j]);
                    *(short4v*)&xt[(4 * c4 + j) * 136 + rg] = pk;
                }
            }
        }
        __syncthreads();
        // wave w owns k-chunk rows 32w..32w+31; one frag per 16-col tile
        bf16x8 f[4];
#pragma unroll
        for (int c0 = 0; c0 < 4; ++c0)
            f[c0] = *(const bf16x8*)&xt[(16 * c0 + (lane & 15)) * 136 + 32 * w + 8 * (lane >> 4)];
#pragma unroll
        for (int p = 0; p < 4; ++p)
#pragma unroll
            for (int q = 0; q < 4; ++q)
                acc[p][q] = __builtin_amdgcn_mfma_f32_16x16x32_bf16(f[p], f[q], acc[p][q], 0, 0, 0);
    }

    __syncthreads();                             // xt dead; reuse smem
    ((float4*)(smem + 4096))[t] = make_float4(s0, s1, s2, s3);
    int qd = lane >> 4, cl = lane & 15;
    if (w == 0) {
#pragma unroll
        for (int p = 0; p < 4; ++p)
#pragma unroll
            for (int q = 0; q < 4; ++q)
#pragma unroll
                for (int i = 0; i < 4; ++i)
                    smem[(16 * p + 4 * qd + i) * 64 + 16 * q + cl] = acc[p][q][i];
    }
    __syncthreads();
    if (t < 64) {                                // wave0: segment-sum reduce + atomic
        int cc4 = t >> 2, ii = t & 3;
        float s = 0;
#pragma unroll
        for (int u = 0; u < 16; ++u) s += smem[4096 + 4 * (cc4 + 16 * u) + ii];
        atomicAdd(&ssumg[seg * 64 + t], s);
    }
    for (int ww = 1; ww < 4; ++ww) {
        if (w == ww) {
#pragma unroll
            for (int p = 0; p < 4; ++p)
#pragma unroll
                for (int q = 0; q < 4; ++q)
#pragma unroll
                    for (int i = 0; i < 4; ++i)
                        smem[(16 * p + 4 * qd + i) * 64 + 16 * q + cl] += acc[p][q][i];
        }
        __syncthreads();
    }
    // per-segment partial buffer; rotation decorrelates same-address bursts
    float* m2seg = m2p + seg * 4096;
#pragma unroll
    for (int ii = 0; ii < 16; ++ii) {
        int f2 = t + 256 * ((ii + blockIdx.x) & 15);
        atomicAdd(&m2seg[f2], smem[f2]);
    }
}

// ---------------- K2b: tiny algebra -> wpb (bf16), tb ----------------
// Single block; all operands staged to LDS in one parallel burst. M2 staging
// sums the 8 per-segment partials (128 KB read, one round trip).
__global__ __launch_bounds__(256)
void k2b_solve(const int* __restrict__ o,
               const float* __restrict__ w2, const float* __restrict__ b2,
               const float* __restrict__ w1, const float* __restrict__ b1,
               const float* __restrict__ gamma, const float* __restrict__ beta,
               const float* __restrict__ m2p, const float* __restrict__ ssum,
               unsigned short* __restrict__ wpb, float* __restrict__ tbout)
{
    __shared__ __align__(16) float w1s[8192];    // 32 KB  w1[c][128]
    __shared__ __align__(16) float w2s[4096];    // 16 KB  w2[c][64]
    __shared__ __align__(16) float m2s[4096];    // 16 KB  M2[j][64]
    __shared__ __align__(16) float ssums[512];
    __shared__ float means[512], hb[512], cv[512], q1p[256];
    __shared__ float Sx[64], muS[64], sS[64], cnts[8];

    int t = threadIdx.x;
    // ---- parallel LDS staging burst ----
    for (int i = t; i < 2048; i += 256) ((float4*)w1s)[i] = ((const float4*)w1)[i];
    for (int i = t; i < 1024; i += 256) ((float4*)w2s)[i] = ((const float4*)w2)[i];
    for (int i = t; i < 1024; i += 256) {        // reduce 8 segment-partials of M2
        float4 a = ((const float4*)m2p)[i];
#pragma unroll
        for (int s = 1; s < 8; ++s) {
            float4 b = ((const float4*)m2p)[s * 1024 + i];
            a.x += b.x; a.y += b.y; a.z += b.z; a.w += b.w;
        }
        ((float4*)m2s)[i] = a;
    }
    for (int i = t; i < 128;  i += 256) ((float4*)ssums)[i] = ((const float4*)ssum)[i];
    if (t < 8) cnts[t] = (float)(o[t] - (t ? o[t - 1] : 0));
    __syncthreads();

    for (int i = t; i < 512; i += 256) means[i] = ssums[i] / cnts[i >> 6];
    __syncthreads();
    int c = t & 63, g = t >> 6;
    for (int b = g; b < 8; b += 4) {
        float a = b2[c];
        for (int k = 0; k < 64; ++k) a = fmaf(means[b * 64 + k], w2s[c * 64 + k], a);
        hb[b * 64 + c] = fmaxf(a, 0.f);
    }
    __syncthreads();
    for (int b = g; b < 8; b += 4) {
        float a = b1[c];
        for (int k = 0; k < 64; ++k) a = fmaf(hb[b * 64 + k], w1s[c * 128 + 64 + k], a);
        cv[b * 64 + c] = a;
    }
    __syncthreads();
    if (t < 64) {
        float s = 0;
        for (int b = 0; b < 8; ++b) s += ssums[b * 64 + t];
        Sx[t] = s;
    }
    __syncthreads();
    {
        float p = 0;
        for (int j = g * 16; j < g * 16 + 16; ++j) {
            float vj = 0;
            for (int k = 0; k < 64; ++k) vj = fmaf(w1s[c * 128 + k], m2s[j * 64 + k], vj);
            p = fmaf(w1s[c * 128 + j], vj, p);
        }
        q1p[g * 64 + c] = p;
    }
    __syncthreads();
    if (t < 64) {
        const float Nf = (float)NROWS;
        float mu = 0;
        for (int k = 0; k < 64; ++k) mu = fmaf(w1s[t * 128 + k], Sx[k], mu);
        float q2 = 0, q3 = 0, msum = 0;
        for (int b = 0; b < 8; ++b) {
            float gv = cv[b * 64 + t];
            msum += cnts[b] * gv;
            q3 = fmaf(cnts[b] * gv, gv, q3);
            float dot = 0;
            for (int k = 0; k < 64; ++k) dot = fmaf(w1s[t * 128 + k], ssums[b * 64 + k], dot);
            q2 = fmaf(2.f * gv, dot, q2);
        }
        mu = (mu + msum) / Nf;
        float q1 = q1p[t] + q1p[64 + t] + q1p[128 + t] + q1p[192 + t];
        float var = (q1 + q2 + q3) / Nf - mu * mu;
        float s = gamma[t] * rsqrtf(var + 1e-5f);
        muS[t] = mu; sS[t] = s;
    }
    __syncthreads();
    for (int f = t; f < 4096; f += 256)         // W'[c][k] bf16, row-major (B-frag ready)
        wpb[f] = f2bf(w1s[(f >> 6) * 128 + (f & 63)] * sS[f >> 6]);
    for (int f = t; f < 512; f += 256)
        tbout[f] = (cv[f] - muS[f & 63]) * sS[f & 63] + beta[f & 63];
}

// ---------------- K3: out = relu(x @ W'^T + tb[seg]) via bf16 MFMA ----------------
// All 16 A-loads hoisted before the convert+MFMA chain: one exposed HBM
// latency per chunk instead of four. launch_bounds(256,2) so the hoisted
// register set (~180 VGPR) does not spill.
__global__ __launch_bounds__(256, 2)
void k3_gemm(const float* __restrict__ x, const unsigned short* __restrict__ wpb,
             const float* __restrict__ tb, float* __restrict__ out)
{
    __shared__ __align__(16) short bt[64 * 72];  // W' tile, stride 72 shorts
    __shared__ float tbs[512];
    int t = threadIdx.x, lane = t & 63, w = t >> 6;
    size_t r0 = (size_t)blockIdx.x * 256;

    for (int f = t; f < 512; f += 256) {         // stage W' (8 KB) to LDS
        int c = f >> 3, kg = f & 7;
        uint4 vv = ((const uint4*)wpb)[f];
        *(uint4*)&bt[c * 72 + kg * 8] = vv;
    }
    for (int f = t; f < 512; f += 256) tbs[f] = tb[f];
    __syncthreads();

    int cl = lane & 15, qd = lane >> 4;
    int rbase = (int)r0 + 64 * w;

    // hoist all 16 A-loads (4 m-rows x 4 float4) into registers
    float4 u[4][4];
#pragma unroll
    for (int m = 0; m < 4; ++m) {
        const float* rp = x + (size_t)(rbase + 16 * m + cl) * 64 + 8 * qd;
        u[m][0] = *(const float4*)(rp);
        u[m][1] = *(const float4*)(rp + 4);
        u[m][2] = *(const float4*)(rp + 32);
        u[m][3] = *(const float4*)(rp + 36);
    }

    bf16x8 B[4][2];
#pragma unroll
    for (int n = 0; n < 4; ++n)
#pragma unroll
        for (int k0 = 0; k0 < 2; ++k0)
            B[n][k0] = *(const bf16x8*)&bt[(16 * n + cl) * 72 + 32 * k0 + 8 * qd];

    f32x4 acc[4][4];
#pragma unroll
    for (int m = 0; m < 4; ++m)
#pragma unroll
        for (int n = 0; n < 4; ++n) acc[m][n] = (f32x4){0.f, 0.f, 0.f, 0.f};

#pragma unroll
    for (int m = 0; m < 4; ++m) {
        bf16x8 A0, A1;
        A0[0] = (short)f2bf(u[m][0].x); A0[1] = (short)f2bf(u[m][0].y);
        A0[2] = (short)f2bf(u[m][0].z); A0[3] = (short)f2bf(u[m][0].w);
        A0[4] = (short)f2bf(u[m][1].x); A0[5] = (short)f2bf(u[m][1].y);
        A0[6] = (short)f2bf(u[m][1].z); A0[7] = (short)f2bf(u[m][1].w);
        A1[0] = (short)f2bf(u[m][2].x); A1[1] = (short)f2bf(u[m][2].y);
        A1[2] = (short)f2bf(u[m][2].z); A1[3] = (short)f2bf(u[m][2].w);
        A1[4] = (short)f2bf(u[m][3].x); A1[5] = (short)f2bf(u[m][3].y);
        A1[6] = (short)f2bf(u[m][3].z); A1[7] = (short)f2bf(u[m][3].w);
#pragma unroll
        for (int n = 0; n < 4; ++n) {
            acc[m][n] = __builtin_amdgcn_mfma_f32_16x16x32_bf16(A0, B[n][0], acc[m][n], 0, 0, 0);
            acc[m][n] = __builtin_amdgcn_mfma_f32_16x16x32_bf16(A1, B[n][1], acc[m][n], 0, 0, 0);
        }
    }

    // epilogue: +tb[seg], relu, direct stores (16 lanes = 64 B runs)
    int seg0 = rbase / SEGROWS;
    int bnd = (seg0 + 1) * SEGROWS;
    int seg1 = min(seg0 + 1, 7);
    float tA[4], tB[4];
#pragma unroll
    for (int n = 0; n < 4; ++n) {
        tA[n] = tbs[seg0 * 64 + 16 * n + cl];
        tB[n] = tbs[seg1 * 64 + 16 * n + cl];
    }
#pragma unroll
    for (int m = 0; m < 4; ++m)
#pragma unroll
        for (int i = 0; i < 4; ++i) {
            int grow = rbase + 16 * m + 4 * qd + i;
            bool hi = grow >= bnd;
#pragma unroll
            for (int n = 0; n < 4; ++n) {
                float tv = hi ? tB[n] : tA[n];
                float vv = fmaxf(acc[m][n][i] + tv, 0.f);
                out[(size_t)grow * 64 + 16 * n + cl] = vv;
            }
        }
}

extern "C" void kernel_launch(void* const* d_in, const int* in_sizes, int n_in,
                              void* d_out, int out_size, void* d_ws, size_t ws_size,
                              hipStream_t stream)
{
    const float* x  = (const float*)d_in[0];
    const int*   o  = (const int*)d_in[1];
    const float* w2 = (const float*)d_in[2];
    const float* b2 = (const float*)d_in[3];
    const float* w1 = (const float*)d_in[4];
    const float* b1 = (const float*)d_in[5];
    const float* gm = (const float*)d_in[6];
    const float* bt = (const float*)d_in[7];
    float* out = (float*)d_out;
    float* ws  = (float*)d_ws;

    float*          m2p  = ws;                    // 8 x 4096 partials
    float*          ssum = ws + 32768;
    float*          tbv  = ws + 33280;
    unsigned short* wpb  = (unsigned short*)(ws + 33792);

    kzero<<<130, 256, 0, stream>>>(ws);
    k1_stats<<<K1_BLOCKS, 256, 0, stream>>>(x, m2p, ssum);
    k2b_solve<<<1, 256, 0, stream>>>(o, w2, b2, w1, b1, gm, bt, m2p, ssum, wpb, tbv);
    k3_gemm<<<3125, 256, 0, stream>>>(x, wpb, tbv, out);
}

// Round 6
// 432.935 us; speedup vs baseline: 1.3237x; 1.0026x over previous
//
#include <hip/hip_runtime.h>

#define NROWS 800000
#define SEGROWS 100000
#define K1_BLOCKS 800
#define K1_ROWS 1000
// ws float layout:
//   [0..32768)       M2 per-segment partials: 8 x 4096 (atomic, fan-in 100)
//   [32768..33280)   segment sums (atomic, fan-in 100)
//   [33280..33792)   tb fp32 (written by k2b)
//   [33792..35840)   wpb: W' as bf16 ushort[64*64], row-major [c][k] (k2b)

typedef __attribute__((ext_vector_type(8))) short bf16x8;
typedef __attribute__((ext_vector_type(4))) float f32x4;

__device__ inline unsigned short f2bf(float f) { // RNE fp32 -> bf16
    unsigned u = __builtin_bit_cast(unsigned, f);
    return (unsigned short)((u + 0x7FFFu + ((u >> 16) & 1u)) >> 16);
}

// ---------------- K0: zero the atomic accumulators ----------------
__global__ void kzero(float* __restrict__ p) {
    int t = blockIdx.x * 256 + threadIdx.x;
    if (t < 33280) p[t] = 0.f;
}

// ---------------- K1: M2 = X^T X (bf16 MFMA) + segment sums ----------------
// BARRIER-FREE main loop: the MFMA fragment frag(l,j)=x[rb+8*(l>>4)+j][16c0+(l&15)]
// is loaded directly from global (per j: 4 rows x 64 contiguous bytes, coalesced;
// the c0 loop consumes full 128-B L2 lines). Each wave owns independent 32-row
// chunks -> 32 outstanding loads/wave, no LDS staging, no syncthreads until the
// epilogue reduce. Column sums accumulate in registers.
__global__ __launch_bounds__(256, 3)
void k1_stats(const float* __restrict__ x, float* __restrict__ m2p, float* __restrict__ ssumg)
{
    __shared__ __align__(16) float smem[4096];   // 16 KB: M2 cross-wave reduce
    __shared__ float red[4][256];                // 4 KB: column-sum reduce
    int t = threadIdx.x, w = t >> 6, lane = t & 63;
    const int lg = lane >> 4, li = lane & 15;
    size_t r0 = (size_t)blockIdx.x * K1_ROWS;
    int seg = (int)(r0 / SEGROWS);               // blocks are segment-aligned (1000 | 100000)

    f32x4 acc[4][4];
#pragma unroll
    for (int p = 0; p < 4; ++p)
#pragma unroll
        for (int q = 0; q < 4; ++q) acc[p][q] = (f32x4){0.f, 0.f, 0.f, 0.f};
    float s[4] = {0.f, 0.f, 0.f, 0.f};

    // 32 chunks of 32 rows cover 1024 >= 1000 rows; wave w takes chunks w, w+4, ...
    for (int ch = w; ch < 32; ch += 4) {
        const int rb = 32 * ch + 8 * lg;         // block-local row base for this lane-group
        const float* xp = x + (r0 + rb) * 64 + li;
        float xv[4][8];
        if (ch < 31) {                           // full chunk: 32 unconditional dword loads
#pragma unroll
            for (int c0 = 0; c0 < 4; ++c0)
#pragma unroll
                for (int j = 0; j < 8; ++j)
                    xv[c0][j] = xp[(size_t)j * 64 + 16 * c0];
        } else {                                 // tail chunk: rows 992..1023, guard at 1000
#pragma unroll
            for (int c0 = 0; c0 < 4; ++c0)
#pragma unroll
                for (int j = 0; j < 8; ++j)
                    xv[c0][j] = (rb + j < K1_ROWS) ? xp[(size_t)j * 64 + 16 * c0] : 0.f;
        }
        bf16x8 f[4];
#pragma unroll
        for (int c0 = 0; c0 < 4; ++c0)
#pragma unroll
            for (int j = 0; j < 8; ++j) {
                s[c0] += xv[c0][j];
                f[c0][j] = (short)f2bf(xv[c0][j]);
            }
#pragma unroll
        for (int p = 0; p < 4; ++p)
#pragma unroll
            for (int q = 0; q < 4; ++q)
                acc[p][q] = __builtin_amdgcn_mfma_f32_16x16x32_bf16(f[p], f[q], acc[p][q], 0, 0, 0);
    }

    // ---- epilogue: column-sum reduce + M2 cross-wave reduce + atomic flush ----
#pragma unroll
    for (int c0 = 0; c0 < 4; ++c0) red[c0][t] = s[c0];
    int qd = lane >> 4, cl = lane & 15;
    if (w == 0) {                                // wave0 seeds the M2 LDS buffer
#pragma unroll
        for (int p = 0; p < 4; ++p)
#pragma unroll
            for (int q = 0; q < 4; ++q)
#pragma unroll
                for (int i = 0; i < 4; ++i)
                    smem[(16 * p + 4 * qd + i) * 64 + 16 * q + cl] = acc[p][q][i];
    }
    __syncthreads();
    if (t < 64) {                                // column c == t (identity mapping)
        int c0 = t >> 4, cc = t & 15;
        float tot = 0;
#pragma unroll
        for (int u = 0; u < 16; ++u)             // sum over 4 waves x 4 lane-groups
            tot += red[c0][(u >> 2) * 64 + (u & 3) * 16 + cc];
        atomicAdd(&ssumg[seg * 64 + t], tot);
    }
    for (int ww = 1; ww < 4; ++ww) {
        if (w == ww) {
#pragma unroll
            for (int p = 0; p < 4; ++p)
#pragma unroll
                for (int q = 0; q < 4; ++q)
#pragma unroll
                    for (int i = 0; i < 4; ++i)
                        smem[(16 * p + 4 * qd + i) * 64 + 16 * q + cl] += acc[p][q][i];
        }
        __syncthreads();
    }
    // per-segment partial buffer; rotation decorrelates same-address bursts
    float* m2seg = m2p + seg * 4096;
#pragma unroll
    for (int ii = 0; ii < 16; ++ii) {
        int f2 = t + 256 * ((ii + blockIdx.x) & 15);
        atomicAdd(&m2seg[f2], smem[f2]);
    }
}

// ---------------- K2b: tiny algebra -> wpb (bf16), tb ----------------
// Single block; all operands staged to LDS in one parallel burst. M2 staging
// sums the 8 per-segment partials (128 KB read, one round trip).
__global__ __launch_bounds__(256)
void k2b_solve(const int* __restrict__ o,
               const float* __restrict__ w2, const float* __restrict__ b2,
               const float* __restrict__ w1, const float* __restrict__ b1,
               const float* __restrict__ gamma, const float* __restrict__ beta,
               const float* __restrict__ m2p, const float* __restrict__ ssum,
               unsigned short* __restrict__ wpb, float* __restrict__ tbout)
{
    __shared__ __align__(16) float w1s[8192];    // 32 KB  w1[c][128]
    __shared__ __align__(16) float w2s[4096];    // 16 KB  w2[c][64]
    __shared__ __align__(16) float m2s[4096];    // 16 KB  M2[j][64]
    __shared__ __align__(16) float ssums[512];
    __shared__ float means[512], hb[512], cv[512], q1p[256];
    __shared__ float Sx[64], muS[64], sS[64], cnts[8];

    int t = threadIdx.x;
    // ---- parallel LDS staging burst ----
    for (int i = t; i < 2048; i += 256) ((float4*)w1s)[i] = ((const float4*)w1)[i];
    for (int i = t; i < 1024; i += 256) ((float4*)w2s)[i] = ((const float4*)w2)[i];
    for (int i = t; i < 1024; i += 256) {        // reduce 8 segment-partials of M2
        float4 a = ((const float4*)m2p)[i];
#pragma unroll
        for (int s = 1; s < 8; ++s) {
            float4 b = ((const float4*)m2p)[s * 1024 + i];
            a.x += b.x; a.y += b.y; a.z += b.z; a.w += b.w;
        }
        ((float4*)m2s)[i] = a;
    }
    for (int i = t; i < 128;  i += 256) ((float4*)ssums)[i] = ((const float4*)ssum)[i];
    if (t < 8) cnts[t] = (float)(o[t] - (t ? o[t - 1] : 0));
    __syncthreads();

    for (int i = t; i < 512; i += 256) means[i] = ssums[i] / cnts[i >> 6];
    __syncthreads();
    int c = t & 63, g = t >> 6;
    for (int b = g; b < 8; b += 4) {
        float a = b2[c];
        for (int k = 0; k < 64; ++k) a = fmaf(means[b * 64 + k], w2s[c * 64 + k], a);
        hb[b * 64 + c] = fmaxf(a, 0.f);
    }
    __syncthreads();
    for (int b = g; b < 8; b += 4) {
        float a = b1[c];
        for (int k = 0; k < 64; ++k) a = fmaf(hb[b * 64 + k], w1s[c * 128 + 64 + k], a);
        cv[b * 64 + c] = a;
    }
    __syncthreads();
    if (t < 64) {
        float s = 0;
        for (int b = 0; b < 8; ++b) s += ssums[b * 64 + t];
        Sx[t] = s;
    }
    __syncthreads();
    {
        float p = 0;
        for (int j = g * 16; j < g * 16 + 16; ++j) {
            float vj = 0;
            for (int k = 0; k < 64; ++k) vj = fmaf(w1s[c * 128 + k], m2s[j * 64 + k], vj);
            p = fmaf(w1s[c * 128 + j], vj, p);
        }
        q1p[g * 64 + c] = p;
    }
    __syncthreads();
    if (t < 64) {
        const float Nf = (float)NROWS;
        float mu = 0;
        for (int k = 0; k < 64; ++k) mu = fmaf(w1s[t * 128 + k], Sx[k], mu);
        float q2 = 0, q3 = 0, msum = 0;
        for (int b = 0; b < 8; ++b) {
            float gv = cv[b * 64 + t];
            msum += cnts[b] * gv;
            q3 = fmaf(cnts[b] * gv, gv, q3);
            float dot = 0;
            for (int k = 0; k < 64; ++k) dot = fmaf(w1s[t * 128 + k], ssums[b * 64 + k], dot);
            q2 = fmaf(2.f * gv, dot, q2);
        }
        mu = (mu + msum) / Nf;
        float q1 = q1p[t] + q1p[64 + t] + q1p[128 + t] + q1p[192 + t];
        float var = (q1 + q2 + q3) / Nf - mu * mu;
        float s = gamma[t] * rsqrtf(var + 1e-5f);
        muS[t] = mu; sS[t] = s;
    }
    __syncthreads();
    for (int f = t; f < 4096; f += 256)         // W'[c][k] bf16, row-major (B-frag ready)
        wpb[f] = f2bf(w1s[(f >> 6) * 128 + (f & 63)] * sS[f >> 6]);
    for (int f = t; f < 512; f += 256)
        tbout[f] = (cv[f] - muS[f & 63]) * sS[f & 63] + beta[f & 63];
}

// ---------------- K3: out = relu(x @ W'^T + tb[seg]) via bf16 MFMA ----------------
// All 16 A-loads hoisted before the convert+MFMA chain.
__global__ __launch_bounds__(256, 2)
void k3_gemm(const float* __restrict__ x, const unsigned short* __restrict__ wpb,
             const float* __restrict__ tb, float* __restrict__ out)
{
    __shared__ __align__(16) short bt[64 * 72];  // W' tile, stride 72 shorts
    __shared__ float tbs[512];
    int t = threadIdx.x, lane = t & 63, w = t >> 6;
    size_t r0 = (size_t)blockIdx.x * 256;

    for (int f = t; f < 512; f += 256) {         // stage W' (8 KB) to LDS
        int c = f >> 3, kg = f & 7;
        uint4 vv = ((const uint4*)wpb)[f];
        *(uint4*)&bt[c * 72 + kg * 8] = vv;
    }
    for (int f = t; f < 512; f += 256) tbs[f] = tb[f];
    __syncthreads();

    int cl = lane & 15, qd = lane >> 4;
    int rbase = (int)r0 + 64 * w;

    // hoist all 16 A-loads (4 m-rows x 4 float4) into registers
    float4 u[4][4];
#pragma unroll
    for (int m = 0; m < 4; ++m) {
        const float* rp = x + (size_t)(rbase + 16 * m + cl) * 64 + 8 * qd;
        u[m][0] = *(const float4*)(rp);
        u[m][1] = *(const float4*)(rp + 4);
        u[m][2] = *(const float4*)(rp + 32);
        u[m][3] = *(const float4*)(rp + 36);
    }

    bf16x8 B[4][2];
#pragma unroll
    for (int n = 0; n < 4; ++n)
#pragma unroll
        for (int k0 = 0; k0 < 2; ++k0)
            B[n][k0] = *(const bf16x8*)&bt[(16 * n + cl) * 72 + 32 * k0 + 8 * qd];

    f32x4 acc[4][4];
#pragma unroll
    for (int m = 0; m < 4; ++m)
#pragma unroll
        for (int n = 0; n < 4; ++n) acc[m][n] = (f32x4){0.f, 0.f, 0.f, 0.f};

#pragma unroll
    for (int m = 0; m < 4; ++m) {
        bf16x8 A0, A1;
        A0[0] = (short)f2bf(u[m][0].x); A0[1] = (short)f2bf(u[m][0].y);
        A0[2] = (short)f2bf(u[m][0].z); A0[3] = (short)f2bf(u[m][0].w);
        A0[4] = (short)f2bf(u[m][1].x); A0[5] = (short)f2bf(u[m][1].y);
        A0[6] = (short)f2bf(u[m][1].z); A0[7] = (short)f2bf(u[m][1].w);
        A1[0] = (short)f2bf(u[m][2].x); A1[1] = (short)f2bf(u[m][2].y);
        A1[2] = (short)f2bf(u[m][2].z); A1[3] = (short)f2bf(u[m][2].w);
        A1[4] = (short)f2bf(u[m][3].x); A1[5] = (short)f2bf(u[m][3].y);
        A1[6] = (short)f2bf(u[m][3].z); A1[7] = (short)f2bf(u[m][3].w);
#pragma unroll
        for (int n = 0; n < 4; ++n) {
            acc[m][n] = __builtin_amdgcn_mfma_f32_16x16x32_bf16(A0, B[n][0], acc[m][n], 0, 0, 0);
            acc[m][n] = __builtin_amdgcn_mfma_f32_16x16x32_bf16(A1, B[n][1], acc[m][n], 0, 0, 0);
        }
    }

    // epilogue: +tb[seg], relu, direct stores (16 lanes = 64 B runs)
    int seg0 = rbase / SEGROWS;
    int bnd = (seg0 + 1) * SEGROWS;
    int seg1 = min(seg0 + 1, 7);
    float tA[4], tB[4];
#pragma unroll
    for (int n = 0; n < 4; ++n) {
        tA[n] = tbs[seg0 * 64 + 16 * n + cl];
        tB[n] = tbs[seg1 * 64 + 16 * n + cl];
    }
#pragma unroll
    for (int m = 0; m < 4; ++m)
#pragma unroll
        for (int i = 0; i < 4; ++i) {
            int grow = rbase + 16 * m + 4 * qd + i;
            bool hi = grow >= bnd;
#pragma unroll
            for (int n = 0; n < 4; ++n) {
                float tv = hi ? tB[n] : tA[n];
                float vv = fmaxf(acc[m][n][i] + tv, 0.f);
                out[(size_t)grow * 64 + 16 * n + cl] = vv;
            }
        }
}

extern "C" void kernel_launch(void* const* d_in, const int* in_sizes, int n_in,
                              void* d_out, int out_size, void* d_ws, size_t ws_size,
                              hipStream_t stream)
{
    const float* x  = (const float*)d_in[0];
    const int*   o  = (const int*)d_in[1];
    const float* w2 = (const float*)d_in[2];
    const float* b2 = (const float*)d_in[3];
    const float* w1 = (const float*)d_in[4];
    const float* b1 = (const float*)d_in[5];
    const float* gm = (const float*)d_in[6];
    const float* bt = (const float*)d_in[7];
    float* out = (float*)d_out;
    float* ws  = (float*)d_ws;

    float*          m2p  = ws;                    // 8 x 4096 partials
    float*          ssum = ws + 32768;
    float*          tbv  = ws + 33280;
    unsigned short* wpb  = (unsigned short*)(ws + 33792);

    kzero<<<130, 256, 0, stream>>>(ws);
    k1_stats<<<K1_BLOCKS, 256, 0, stream>>>(x, m2p, ssum);
    k2b_solve<<<1, 256, 0, stream>>>(o, w2, b2, w1, b1, gm, bt, m2p, ssum, wpb, tbv);
    k3_gemm<<<3125, 256, 0, stream>>>(x, wpb, tbv, out);
}